// Round 12
// baseline (298.542 us; speedup 1.0000x reference)
//
#include <hip/hip_runtime.h>
#include <hip/hip_bf16.h>
#include <hip/hip_fp16.h>
#include <math.h>

// R24: DIAGNOSTIC + A/B. Three consecutive neutral rounds at 85.1x with
// structurally different kernels = hard floor; attn (f16) never profiled
// (R22: gemm rows crowded it out). This round: (a) attn af-gen via inline-asm
// v_pk_mul_f16 x2 + v_pk_max_f16 (tests the "clang scalarizes f16x2" theory
// in-place, bit-identical math); (b) rep-loops sized so BOTH kernels crack
// the 43us fills: gemm reps=10 (~60-100us), attn reps=16 (~150-220us).
// Laundering: z = reps>>8 == 0 runtime, opaque (proven R16/R22).
// dur_us is a throwaway. Readings pre-committed in journal.

// Problem constants
#define F_IN  256
#define NOUT  256          // N_HEADS * N_HIDDEN
#define NB    8            // batch
#define NN    1024         // nodes
#define NH    8            // heads
#define ND    32           // hidden per head
#define NROWS (NB * NN)    // 8192
#define LOG2E 1.44269504f

typedef __attribute__((ext_vector_type(8))) short bf16x8;       // 8 bf16
typedef __attribute__((ext_vector_type(8))) _Float16 f16x8;     // 8 f16
typedef __attribute__((ext_vector_type(2))) _Float16 f16x2;     // packed f16
typedef __attribute__((ext_vector_type(4))) float f32x4;        // MFMA C/D

__device__ inline unsigned pk_f16(float a, float b) {
    union { __half2 h2; unsigned u; } c;
    c.h2 = __float22half2_rn(make_float2(a, b));
    return c.u;
}

// guaranteed packed-f16 ops (bit patterns in unsigned)
__device__ __forceinline__ unsigned pkmul(unsigned a, unsigned b) {
    unsigned r;
    asm("v_pk_mul_f16 %0, %1, %2" : "=v"(r) : "v"(a), "v"(b));
    return r;
}
__device__ __forceinline__ unsigned pkmax(unsigned a, unsigned b) {
    unsigned r;
    asm("v_pk_max_f16 %0, %1, %2" : "=v"(r) : "v"(a), "v"(b));
    return r;
}

// ---------------------------------------------------------------------------
// Kernel 1: gemm (R23 single-pass f16 body, rep-looped for profiling)
// ---------------------------------------------------------------------------
__global__ __launch_bounds__(256, 4) void gat_gemm_kernel(
    const float* __restrict__ vertex0, const float* __restrict__ w_vert0,
    const float* __restrict__ attn_w0, unsigned short* __restrict__ gT0,
    float* __restrict__ ssT0, float* __restrict__ sdT0, int reps)
{
    __shared__ __align__(16) unsigned short bHi[8192];
    f32x4 (*comb)[4][64] = reinterpret_cast<f32x4(*)[4][64]>(bHi);
    unsigned short (*trans)[72] =
        reinterpret_cast<unsigned short(*)[72]>(bHi + 4096);

    const int t = threadIdx.x, lane = t & 63, wv = t >> 6;
    const int mt = wv & 1, kh = wv >> 1;
    const int il = lane & 15, ql = lane >> 4;
    const int h = blockIdx.y, gr0 = blockIdx.x * 64;
    const int b = gr0 >> 10, bh = b * NH + h;

    const size_t z = (size_t)(reps >> 8);   // 0 at runtime, opaque

    for (int r = 0; r < reps; ++r) {
        const size_t zo = z * (size_t)(r + 1);
        const float* vertex = vertex0 + zo;
        const float* w_vert = w_vert0 + zo;
        const float* attn_w = attn_w0 + zo;
        unsigned short* gT = gT0 + zo;
        float* ssT = ssT0 + zo;
        float* sdT = sdT0 + zo;

        {
            const int n  = t & 31;
            const int kb = t >> 5;               // 0..7
            const int il_s = n & 15, nt_s = n >> 4;
            #pragma unroll
            for (int q = 0; q < 4; ++q) {
                const int k0 = kb * 8 + 64 * q;
                const float* wp = w_vert + (size_t)k0 * NOUT + h * 32 + n;
                float f[8];
                #pragma unroll
                for (int j = 0; j < 8; ++j) f[j] = wp[j * NOUT];
                unsigned hu[4];
                #pragma unroll
                for (int j2 = 0; j2 < 4; ++j2)
                    hu[j2] = pk_f16(f[2 * j2], f[2 * j2 + 1]);
                const int ktile = k0 >> 5;
                const int qlb   = (k0 & 31) >> 3;
                const int off   = (ktile * 2 + nt_s) * 512 + (qlb * 16 + il_s) * 8;
                *(uint4*)&bHi[off] = *(const uint4*)hu;
            }
        }
        __syncthreads();

        const float* arow0 = vertex + (size_t)(gr0 + mt * 32 + il) * F_IN + kh * 128 + ql * 8;
        const float* arow1 = arow0 + 16 * F_IN;

        f32x4 c00 = {0.f, 0.f, 0.f, 0.f}, c01 = c00, c10 = c00, c11 = c00;

        #pragma unroll
        for (int kk = 0; kk < 4; ++kk) {
            float4 a0a = *(const float4*)(arow0 + kk * 32);
            float4 a0b = *(const float4*)(arow0 + kk * 32 + 4);
            float4 a1a = *(const float4*)(arow1 + kk * 32);
            float4 a1b = *(const float4*)(arow1 + kk * 32 + 4);

            const int bkb = (kh * 4 + kk) * 2;
            f16x8 bh0 = *(const f16x8*)&bHi[bkb * 512 + lane * 8];
            f16x8 bh1 = *(const f16x8*)&bHi[(bkb + 1) * 512 + lane * 8];

            union { f16x8 v; unsigned u[4]; } A0, A1;
            A0.u[0] = pk_f16(a0a.x, a0a.y); A0.u[1] = pk_f16(a0a.z, a0a.w);
            A0.u[2] = pk_f16(a0b.x, a0b.y); A0.u[3] = pk_f16(a0b.z, a0b.w);
            A1.u[0] = pk_f16(a1a.x, a1a.y); A1.u[1] = pk_f16(a1a.z, a1a.w);
            A1.u[2] = pk_f16(a1b.x, a1b.y); A1.u[3] = pk_f16(a1b.z, a1b.w);

            c00 = __builtin_amdgcn_mfma_f32_16x16x32_f16(A0.v, bh0, c00, 0, 0, 0);
            c01 = __builtin_amdgcn_mfma_f32_16x16x32_f16(A0.v, bh1, c01, 0, 0, 0);
            c10 = __builtin_amdgcn_mfma_f32_16x16x32_f16(A1.v, bh0, c10, 0, 0, 0);
            c11 = __builtin_amdgcn_mfma_f32_16x16x32_f16(A1.v, bh1, c11, 0, 0, 0);
        }

        __syncthreads();
        if (kh == 1) {
            comb[mt][0][lane] = c00; comb[mt][1][lane] = c01;
            comb[mt][2][lane] = c10; comb[mt][3][lane] = c11;
        }
        __syncthreads();
        if (kh == 0) {
            c00 = c00 + comb[mt][0][lane]; c01 = c01 + comb[mt][1][lane];
            c10 = c10 + comb[mt][2][lane]; c11 = c11 + comb[mt][3][lane];

            const float wsv0 = attn_w[il],      wsv1 = attn_w[16 + il];
            const float wdv0 = attn_w[ND + il], wdv1 = attn_w[ND + 16 + il];
            const int j0 = (gr0 & 1023) + mt * 32;

            #pragma unroll
            for (int g = 0; g < 2; ++g) {
                f32x4 cA = g ? c10 : c00;   // d = il
                f32x4 cB = g ? c11 : c01;   // d = 16+il
                const int jl = mt * 32 + g * 16 + ql * 4;

                *(unsigned*)&trans[il][jl]          = pk_f16(cA[0], cA[1]);
                *(unsigned*)&trans[il][jl + 2]      = pk_f16(cA[2], cA[3]);
                *(unsigned*)&trans[16 + il][jl]     = pk_f16(cB[0], cB[1]);
                *(unsigned*)&trans[16 + il][jl + 2] = pk_f16(cB[2], cB[3]);

                const int jr = j0 + g * 16 + ql * 4;
                #pragma unroll
                for (int reg = 0; reg < 4; ++reg) {
                    float ps = cA[reg] * wsv0 + cB[reg] * wsv1;
                    float pd = cA[reg] * wdv0 + cB[reg] * wdv1;
                    #pragma unroll
                    for (int off = 1; off < 16; off <<= 1) {
                        ps += __shfl_xor(ps, off);
                        pd += __shfl_xor(pd, off);
                    }
                    if (il == 0) {
                        ssT[bh * NN + jr + reg] = ps;
                        sdT[bh * NN + jr + reg] = pd;
                    }
                }
            }
        }
        __syncthreads();

        {
            const int d  = t >> 3;
            const int jo = (t & 7) * 8;
            uint4 v = *(const uint4*)&trans[d][jo];
            *(uint4*)(gT + ((size_t)(bh * ND) + d) * NN + (gr0 & 1023) + jo) = v;
        }
        __syncthreads();   // protect staging-LDS reuse across reps
    }
}

// ---------------------------------------------------------------------------
// Kernel 2: attn (R21 pipelined structure, af-gen via inline-asm v_pk ops,
// rep-looped for profiling)
// ---------------------------------------------------------------------------
__global__ __launch_bounds__(256, 4) void gat_attn_kernel(
    const unsigned short* __restrict__ gT0, const float* __restrict__ ssT0,
    const float* __restrict__ sdT0, float* __restrict__ out0, int reps)
{
    __shared__ __align__(16) unsigned short BpH[NN];   // 2 KB, f16 bits
    __shared__ __align__(16) unsigned short BnH[NN];   // 2 KB, f16 bits
    __shared__ f32x4 ccomb[2][12][64];                 // 24 KB
    __shared__ float red[4];

    const int bid = blockIdx.x;
    const int bh = bid & 63;                 // b*NH + h  (bid%8 = h)
    const int b = bh >> 3, h = bh & 7;
    const int i0 = (bid >> 6) * 64;
    const int t = threadIdx.x, lane = t & 63, jq = t >> 6;
    const int il = lane & 15, ql = lane >> 4;

    const size_t z = (size_t)(reps >> 8);   // 0 at runtime, opaque

    for (int r = 0; r < reps; ++r) {
        const size_t zo = z * (size_t)(r + 1);
        const unsigned short* gT = gT0 + zo;
        const float* ssT = ssT0 + zo;
        const float* sdT = sdT0 + zo;
        float* out = out0 + zo;

        float sdv[4]; float M = -3.0e38f;
        #pragma unroll
        for (int q = 0; q < 4; ++q) {
            sdv[q] = sdT[bh * NN + t + 256 * q];
            M = fmaxf(M, sdv[q]);
        }
        #pragma unroll
        for (int off = 32; off >= 1; off >>= 1)
            M = fmaxf(M, __shfl_xor(M, off));
        if (lane == 0) red[jq] = M;
        #pragma unroll
        for (int q = 0; q < 4; ++q) {
            union { _Float16 h; unsigned short u; } cp, cn;
            cp.h = (_Float16)exp2f(sdv[q] * LOG2E);
            cn.h = (_Float16)exp2f(0.2f * LOG2E * sdv[q]);
            BpH[t + 256 * q] = cp.u;
            BnH[t + 256 * q] = cn.u;
        }
        __syncthreads();
        M = fmaxf(fmaxf(red[0], red[1]), fmaxf(red[2], red[3]));

        unsigned apw[4], anw[4];   // f16x2 splats as bit patterns
        #pragma unroll
        for (int mt = 0; mt < 4; ++mt) {
            const float si = ssT[bh * NN + i0 + mt * 16 + il];
            float x = si + M; x = fmaxf(x, 0.2f * x);
            const float mk = x * LOG2E;
            const float ah = exp2f(fmaf(si, LOG2E, -mk));
            const float nh = exp2f(fmaf(0.2f * si, LOG2E, -mk));
            apw[mt] = pk_f16(ah, ah);
            anw[mt] = pk_f16(nh, nh);
        }

        const unsigned short* gb0 = gT + ((size_t)(bh * ND) + il) * NN + jq * 256 + ql * 8;
        const unsigned short* gb1 = gb0 + 16 * NN;
        const unsigned short* bpq = BpH + jq * 256 + ql * 8;
        const unsigned short* bnq = BnH + jq * 256 + ql * 8;

        union { f16x8 v; unsigned u[4]; } ones;
        ones.u[0] = ones.u[1] = ones.u[2] = ones.u[3] = 0x3C003C00u;  // f16 1.0

        f32x4 c0[4], c1[4], cs[4];
        #pragma unroll
        for (int mt = 0; mt < 4; ++mt) {
            c0[mt] = (f32x4){0.f, 0.f, 0.f, 0.f};
            c1[mt] = c0[mt]; cs[mt] = c0[mt];
        }

        // software-pipelined kk loop (gT depth 4, LDS depth 2)
        f16x8 b0b[4], b1b[4];
        union { uint4 q; unsigned w[4]; } pwb[2], nwb[2];
        #pragma unroll
        for (int s = 0; s < 4; ++s) {
            b0b[s] = *(const f16x8*)(gb0 + s * 32);
            b1b[s] = *(const f16x8*)(gb1 + s * 32);
        }
        #pragma unroll
        for (int s = 0; s < 2; ++s) {
            pwb[s].q = *(const uint4*)(bpq + s * 32);
            nwb[s].q = *(const uint4*)(bnq + s * 32);
        }

        #pragma unroll
        for (int s = 0; s < 8; ++s) {
            const int gbi = s & 3, lbi = s & 1;
            const f16x8 bf0 = b0b[gbi];
            const f16x8 bf1 = b1b[gbi];
            unsigned pw0 = pwb[lbi].w[0], pw1 = pwb[lbi].w[1];
            unsigned pw2 = pwb[lbi].w[2], pw3 = pwb[lbi].w[3];
            unsigned nw0 = nwb[lbi].w[0], nw1 = nwb[lbi].w[1];
            unsigned nw2 = nwb[lbi].w[2], nw3 = nwb[lbi].w[3];

            if (s < 4) {
                b0b[gbi] = *(const f16x8*)(gb0 + (s + 4) * 32);
                b1b[gbi] = *(const f16x8*)(gb1 + (s + 4) * 32);
            }
            if (s < 6) {
                pwb[lbi].q = *(const uint4*)(bpq + (s + 2) * 32);
                nwb[lbi].q = *(const uint4*)(bnq + (s + 2) * 32);
            }

            const unsigned pww[4] = {pw0, pw1, pw2, pw3};
            const unsigned nww[4] = {nw0, nw1, nw2, nw3};
            #pragma unroll
            for (int mt = 0; mt < 4; ++mt) {
                union { f16x8 v; unsigned u[4]; } af;
                #pragma unroll
                for (int u = 0; u < 4; ++u)
                    af.u[u] = pkmax(pkmul(pww[u], apw[mt]),
                                    pkmul(nww[u], anw[mt]));
                c0[mt] = __builtin_amdgcn_mfma_f32_16x16x32_f16(af.v, bf0, c0[mt], 0, 0, 0);
                c1[mt] = __builtin_amdgcn_mfma_f32_16x16x32_f16(af.v, bf1, c1[mt], 0, 0, 0);
                cs[mt] = __builtin_amdgcn_mfma_f32_16x16x32_f16(af.v, ones.v, cs[mt], 0, 0, 0);
            }
        }

        if (jq >= 2) {
            #pragma unroll
            for (int mt = 0; mt < 4; ++mt) {
                ccomb[jq - 2][mt * 3 + 0][lane] = c0[mt];
                ccomb[jq - 2][mt * 3 + 1][lane] = c1[mt];
                ccomb[jq - 2][mt * 3 + 2][lane] = cs[mt];
            }
        }
        __syncthreads();
        if (jq < 2) {
            #pragma unroll
            for (int mt = 0; mt < 4; ++mt) {
                c0[mt] = c0[mt] + ccomb[jq][mt * 3 + 0][lane];
                c1[mt] = c1[mt] + ccomb[jq][mt * 3 + 1][lane];
                cs[mt] = cs[mt] + ccomb[jq][mt * 3 + 2][lane];
            }
        }
        __syncthreads();
        if (jq == 1) {
            #pragma unroll
            for (int mt = 0; mt < 4; ++mt) {
                ccomb[0][mt * 3 + 0][lane] = c0[mt];
                ccomb[0][mt * 3 + 1][lane] = c1[mt];
                ccomb[0][mt * 3 + 2][lane] = cs[mt];
            }
        }
        __syncthreads();
        if (jq == 0) {
            #pragma unroll
            for (int mt = 0; mt < 4; ++mt) {
                c0[mt] = c0[mt] + ccomb[0][mt * 3 + 0][lane];
                c1[mt] = c1[mt] + ccomb[0][mt * 3 + 1][lane];
                cs[mt] = cs[mt] + ccomb[0][mt * 3 + 2][lane];

                float* ob = out + (size_t)(b * NN + i0 + mt * 16 + ql * 4) * NOUT + h * ND + il;
                #pragma unroll
                for (int reg = 0; reg < 4; ++reg) {
                    const float rr = 1.0f / cs[mt][reg];
                    ob[reg * NOUT]      = c0[mt][reg] * rr;
                    ob[reg * NOUT + 16] = c1[mt][reg] * rr;
                }
            }
        }
        __syncthreads();   // keep reps cleanly separated (ccomb reuse)
    }
}

// ---------------------------------------------------------------------------
extern "C" void kernel_launch(void* const* d_in, const int* in_sizes, int n_in,
                              void* d_out, int out_size, void* d_ws, size_t ws_size,
                              hipStream_t stream) {
    (void)in_sizes; (void)n_in; (void)out_size; (void)ws_size;
    const float* vertex = (const float*)d_in[0];
    const float* w_vert = (const float*)d_in[1];
    const float* attn_w = (const float*)d_in[2];
    float* out = (float*)d_out;

    char* ws = (char*)d_ws;
    unsigned short* gT = (unsigned short*)ws;                          // 4 MB
    float* ssT = (float*)(ws + ((size_t)NB * NH * ND * NN * 2));
    float* sdT = ssT + (size_t)NB * NH * NN;

    // R24 DIAGNOSTIC: gemm reps=10 (~60-100us), attn reps=16 (~150-220us)
    // -> both crack the ~43us fill rows this time.
    gat_gemm_kernel<<<dim3(128, NH), 256, 0, stream>>>(vertex, w_vert, attn_w,
                                                       gT, ssT, sdT, 10);
    gat_attn_kernel<<<1024, 256, 0, stream>>>(gT, ssT, sdT, out, 16);
}

// Round 13
// 84.299 us; speedup vs baseline: 3.5415x; 3.5415x over previous
//
#include <hip/hip_runtime.h>
#include <hip/hip_bf16.h>
#include <hip/hip_fp16.h>
#include <math.h>

// R25: PRODUCTION of the R24-validated attn pk-asm path (single-shot).
// R24 counters: attn 10.75us/rep warm, VALUBusy 52%, MfmaUtil 26%, 0 bank
// conflicts -> stall-bound; VALU tallest pole. pk-asm af-gen (v_pk_mul_f16
// x2 + v_pk_max_f16) is correctness-proven (absmax bit-identical) but was
// never benched single-shot: R23's production used __builtin_elementwise_max.
// One change vs R23: attn af-gen -> inline-asm pk ops. Gemm = R23 exact.
// Predict dur 85.1 -> ~82-83 if the pk lowering is real; flat -> declare
// practical floor next round (fills ~46 + gaps ~20 + kernels ~17).

// Problem constants
#define F_IN  256
#define NOUT  256          // N_HEADS * N_HIDDEN
#define NB    8            // batch
#define NN    1024         // nodes
#define NH    8            // heads
#define ND    32           // hidden per head
#define NROWS (NB * NN)    // 8192
#define LOG2E 1.44269504f

typedef __attribute__((ext_vector_type(8))) short bf16x8;       // 8 bf16
typedef __attribute__((ext_vector_type(8))) _Float16 f16x8;     // 8 f16
typedef __attribute__((ext_vector_type(2))) _Float16 f16x2;     // packed f16
typedef __attribute__((ext_vector_type(4))) float f32x4;        // MFMA C/D

__device__ inline unsigned pk_f16(float a, float b) {
    union { __half2 h2; unsigned u; } c;
    c.h2 = __float22half2_rn(make_float2(a, b));
    return c.u;
}

// guaranteed packed-f16 ops (bit patterns in unsigned)
__device__ __forceinline__ unsigned pkmul(unsigned a, unsigned b) {
    unsigned r;
    asm("v_pk_mul_f16 %0, %1, %2" : "=v"(r) : "v"(a), "v"(b));
    return r;
}
__device__ __forceinline__ unsigned pkmax(unsigned a, unsigned b) {
    unsigned r;
    asm("v_pk_max_f16 %0, %1, %2" : "=v"(r) : "v"(a), "v"(b));
    return r;
}

// ---------------------------------------------------------------------------
// Kernel 1: g = vertex @ w_vert via single-pass f16 MFMA, split-k 2-way.
// Byte-identical to R23.
// ---------------------------------------------------------------------------
__global__ __launch_bounds__(256, 4) void gat_gemm_kernel(
    const float* __restrict__ vertex, const float* __restrict__ w_vert,
    const float* __restrict__ attn_w, unsigned short* __restrict__ gT,
    float* __restrict__ ssT, float* __restrict__ sdT)
{
    // staging: [bk(16 blocks: ktile*2+nt)][lane(64)][8 f16] = 16 KB
    __shared__ __align__(16) unsigned short bHi[8192];
    f32x4 (*comb)[4][64] = reinterpret_cast<f32x4(*)[4][64]>(bHi);
    unsigned short (*trans)[72] =
        reinterpret_cast<unsigned short(*)[72]>(bHi + 4096);

    const int t = threadIdx.x, lane = t & 63, wv = t >> 6;
    const int mt = wv & 1, kh = wv >> 1;
    const int il = lane & 15, ql = lane >> 4;
    const int h = blockIdx.y, gr0 = blockIdx.x * 64;
    const int b = gr0 >> 10, bh = b * NH + h;

    {
        const int n  = t & 31;
        const int kb = t >> 5;               // 0..7
        const int il_s = n & 15, nt_s = n >> 4;
        #pragma unroll
        for (int q = 0; q < 4; ++q) {
            const int k0 = kb * 8 + 64 * q;  // 8-aligned, covers 0..255
            const float* wp = w_vert + (size_t)k0 * NOUT + h * 32 + n;
            float f[8];
            #pragma unroll
            for (int j = 0; j < 8; ++j) f[j] = wp[j * NOUT];
            unsigned hu[4];
            #pragma unroll
            for (int j2 = 0; j2 < 4; ++j2)
                hu[j2] = pk_f16(f[2 * j2], f[2 * j2 + 1]);
            const int ktile = k0 >> 5;           // 0..7
            const int qlb   = (k0 & 31) >> 3;    // 0..3
            const int off   = (ktile * 2 + nt_s) * 512 + (qlb * 16 + il_s) * 8;
            *(uint4*)&bHi[off] = *(const uint4*)hu;
        }
    }
    __syncthreads();

    const float* arow0 = vertex + (size_t)(gr0 + mt * 32 + il) * F_IN + kh * 128 + ql * 8;
    const float* arow1 = arow0 + 16 * F_IN;

    f32x4 c00 = {0.f, 0.f, 0.f, 0.f}, c01 = c00, c10 = c00, c11 = c00;

    #pragma unroll
    for (int kk = 0; kk < 4; ++kk) {
        float4 a0a = *(const float4*)(arow0 + kk * 32);
        float4 a0b = *(const float4*)(arow0 + kk * 32 + 4);
        float4 a1a = *(const float4*)(arow1 + kk * 32);
        float4 a1b = *(const float4*)(arow1 + kk * 32 + 4);

        const int bkb = (kh * 4 + kk) * 2;
        f16x8 bh0 = *(const f16x8*)&bHi[bkb * 512 + lane * 8];
        f16x8 bh1 = *(const f16x8*)&bHi[(bkb + 1) * 512 + lane * 8];

        union { f16x8 v; unsigned u[4]; } A0, A1;
        A0.u[0] = pk_f16(a0a.x, a0a.y); A0.u[1] = pk_f16(a0a.z, a0a.w);
        A0.u[2] = pk_f16(a0b.x, a0b.y); A0.u[3] = pk_f16(a0b.z, a0b.w);
        A1.u[0] = pk_f16(a1a.x, a1a.y); A1.u[1] = pk_f16(a1a.z, a1a.w);
        A1.u[2] = pk_f16(a1b.x, a1b.y); A1.u[3] = pk_f16(a1b.z, a1b.w);

        c00 = __builtin_amdgcn_mfma_f32_16x16x32_f16(A0.v, bh0, c00, 0, 0, 0);
        c01 = __builtin_amdgcn_mfma_f32_16x16x32_f16(A0.v, bh1, c01, 0, 0, 0);
        c10 = __builtin_amdgcn_mfma_f32_16x16x32_f16(A1.v, bh0, c10, 0, 0, 0);
        c11 = __builtin_amdgcn_mfma_f32_16x16x32_f16(A1.v, bh1, c11, 0, 0, 0);
    }

    // staging LDS dead from here; alias as combine + transpose buffers
    __syncthreads();
    if (kh == 1) {
        comb[mt][0][lane] = c00; comb[mt][1][lane] = c01;
        comb[mt][2][lane] = c10; comb[mt][3][lane] = c11;
    }
    __syncthreads();
    if (kh == 0) {
        c00 = c00 + comb[mt][0][lane]; c01 = c01 + comb[mt][1][lane];
        c10 = c10 + comb[mt][2][lane]; c11 = c11 + comb[mt][3][lane];

        const float wsv0 = attn_w[il],      wsv1 = attn_w[16 + il];
        const float wdv0 = attn_w[ND + il], wdv1 = attn_w[ND + 16 + il];
        const int j0 = (gr0 & 1023) + mt * 32;

        #pragma unroll
        for (int g = 0; g < 2; ++g) {
            f32x4 cA = g ? c10 : c00;   // d = il
            f32x4 cB = g ? c11 : c01;   // d = 16+il
            const int jl = mt * 32 + g * 16 + ql * 4;   // local j in [0,64)

            // transpose into padded LDS — g stored as f16
            *(unsigned*)&trans[il][jl]          = pk_f16(cA[0], cA[1]);
            *(unsigned*)&trans[il][jl + 2]      = pk_f16(cA[2], cA[3]);
            *(unsigned*)&trans[16 + il][jl]     = pk_f16(cB[0], cB[1]);
            *(unsigned*)&trans[16 + il][jl + 2] = pk_f16(cB[2], cB[3]);

            const int jr = j0 + g * 16 + ql * 4;
            #pragma unroll
            for (int reg = 0; reg < 4; ++reg) {
                float ps = cA[reg] * wsv0 + cB[reg] * wsv1;
                float pd = cA[reg] * wdv0 + cB[reg] * wdv1;
                #pragma unroll
                for (int off = 1; off < 16; off <<= 1) {
                    ps += __shfl_xor(ps, off);
                    pd += __shfl_xor(pd, off);
                }
                if (il == 0) {
                    ssT[bh * NN + jr + reg] = ps;
                    sdT[bh * NN + jr + reg] = pd;
                }
            }
        }
    }
    __syncthreads();

    // coalesced gT store: thread t -> d = t>>3, 8 consecutive j (16 B)
    {
        const int d  = t >> 3;
        const int jo = (t & 7) * 8;
        uint4 v = *(const uint4*)&trans[d][jo];
        *(uint4*)(gT + ((size_t)(bh * ND) + d) * NN + (gr0 & 1023) + jo) = v;
    }
}

// ---------------------------------------------------------------------------
// Kernel 2 (exp-free MFMA attn, packed-f16 P path via inline-asm pk ops,
// R21 pipelined loads — R24 body, single-shot):
// ---------------------------------------------------------------------------
__global__ __launch_bounds__(256, 4) void gat_attn_kernel(
    const unsigned short* __restrict__ gT, const float* __restrict__ ssT,
    const float* __restrict__ sdT, float* __restrict__ out)
{
    __shared__ __align__(16) unsigned short BpH[NN];   // 2 KB, f16 bits
    __shared__ __align__(16) unsigned short BnH[NN];   // 2 KB, f16 bits
    __shared__ f32x4 ccomb[2][12][64];                 // 24 KB
    __shared__ float red[4];

    const int bid = blockIdx.x;
    const int bh = bid & 63;                 // b*NH + h  (bid%8 = h)
    const int b = bh >> 3, h = bh & 7;
    const int i0 = (bid >> 6) * 64;
    const int t = threadIdx.x, lane = t & 63, jq = t >> 6;
    const int il = lane & 15, ql = lane >> 4;

    // ---- phase 0: BpH/BnH (f16) + global sd max + per-lane i-constants ----
    float sdv[4]; float M = -3.0e38f;
    #pragma unroll
    for (int q = 0; q < 4; ++q) {
        sdv[q] = sdT[bh * NN + t + 256 * q];
        M = fmaxf(M, sdv[q]);
    }
    #pragma unroll
    for (int off = 32; off >= 1; off >>= 1)
        M = fmaxf(M, __shfl_xor(M, off));
    if (lane == 0) red[jq] = M;
    #pragma unroll
    for (int q = 0; q < 4; ++q) {
        union { _Float16 h; unsigned short u; } cp, cn;
        cp.h = (_Float16)exp2f(sdv[q] * LOG2E);
        cn.h = (_Float16)exp2f(0.2f * LOG2E * sdv[q]);
        BpH[t + 256 * q] = cp.u;
        BnH[t + 256 * q] = cn.u;
    }
    __syncthreads();
    M = fmaxf(fmaxf(red[0], red[1]), fmaxf(red[2], red[3]));

    unsigned apw[4], anw[4];   // f16x2 splats as bit patterns
    #pragma unroll
    for (int mt = 0; mt < 4; ++mt) {
        const float si = ssT[bh * NN + i0 + mt * 16 + il];
        float x = si + M; x = fmaxf(x, 0.2f * x);
        const float mk = x * LOG2E;
        const float ah = exp2f(fmaf(si, LOG2E, -mk));
        const float nh = exp2f(fmaf(0.2f * si, LOG2E, -mk));
        apw[mt] = pk_f16(ah, ah);
        anw[mt] = pk_f16(nh, nh);
    }

    const unsigned short* gb0 = gT + ((size_t)(bh * ND) + il) * NN + jq * 256 + ql * 8;
    const unsigned short* gb1 = gb0 + 16 * NN;
    const unsigned short* bpq = BpH + jq * 256 + ql * 8;
    const unsigned short* bnq = BnH + jq * 256 + ql * 8;

    union { f16x8 v; unsigned u[4]; } ones;
    ones.u[0] = ones.u[1] = ones.u[2] = ones.u[3] = 0x3C003C00u;   // f16 1.0

    f32x4 c0[4], c1[4], cs[4];
    #pragma unroll
    for (int mt = 0; mt < 4; ++mt) {
        c0[mt] = (f32x4){0.f, 0.f, 0.f, 0.f};
        c1[mt] = c0[mt]; cs[mt] = c0[mt];
    }

    // ---- main loop: wave jq handles j in [jq*256, jq*256+256) ----
    // Software pipeline: gT (global) prefetch depth 4, Bp/Bn (LDS) depth 2.
    f16x8 b0b[4], b1b[4];
    union { uint4 q; unsigned w[4]; } pwb[2], nwb[2];
    #pragma unroll
    for (int s = 0; s < 4; ++s) {
        b0b[s] = *(const f16x8*)(gb0 + s * 32);
        b1b[s] = *(const f16x8*)(gb1 + s * 32);
    }
    #pragma unroll
    for (int s = 0; s < 2; ++s) {
        pwb[s].q = *(const uint4*)(bpq + s * 32);
        nwb[s].q = *(const uint4*)(bnq + s * 32);
    }

    #pragma unroll
    for (int s = 0; s < 8; ++s) {
        const int gbi = s & 3, lbi = s & 1;
        const f16x8 bf0 = b0b[gbi];
        const f16x8 bf1 = b1b[gbi];
        unsigned pw0 = pwb[lbi].w[0], pw1 = pwb[lbi].w[1];
        unsigned pw2 = pwb[lbi].w[2], pw3 = pwb[lbi].w[3];
        unsigned nw0 = nwb[lbi].w[0], nw1 = nwb[lbi].w[1];
        unsigned nw2 = nwb[lbi].w[2], nw3 = nwb[lbi].w[3];

        if (s < 4) {   // prefetch gT for s+4
            b0b[gbi] = *(const f16x8*)(gb0 + (s + 4) * 32);
            b1b[gbi] = *(const f16x8*)(gb1 + (s + 4) * 32);
        }
        if (s < 6) {   // prefetch Bp/Bn for s+2
            pwb[lbi].q = *(const uint4*)(bpq + (s + 2) * 32);
            nwb[lbi].q = *(const uint4*)(bnq + (s + 2) * 32);
        }

        const unsigned pww[4] = {pw0, pw1, pw2, pw3};
        const unsigned nww[4] = {nw0, nw1, nw2, nw3};
        #pragma unroll
        for (int mt = 0; mt < 4; ++mt) {
            union { f16x8 v; unsigned u[4]; } af;
            #pragma unroll
            for (int u = 0; u < 4; ++u)
                af.u[u] = pkmax(pkmul(pww[u], apw[mt]),
                                pkmul(nww[u], anw[mt]));
            c0[mt] = __builtin_amdgcn_mfma_f32_16x16x32_f16(af.v, bf0, c0[mt], 0, 0, 0);
            c1[mt] = __builtin_amdgcn_mfma_f32_16x16x32_f16(af.v, bf1, c1[mt], 0, 0, 0);
            cs[mt] = __builtin_amdgcn_mfma_f32_16x16x32_f16(af.v, ones.v, cs[mt], 0, 0, 0);
        }
    }

    // ---- quarter-combine tree: 2,3 -> 0,1; then 1 -> 0 ----
    if (jq >= 2) {
        #pragma unroll
        for (int mt = 0; mt < 4; ++mt) {
            ccomb[jq - 2][mt * 3 + 0][lane] = c0[mt];
            ccomb[jq - 2][mt * 3 + 1][lane] = c1[mt];
            ccomb[jq - 2][mt * 3 + 2][lane] = cs[mt];
        }
    }
    __syncthreads();
    if (jq < 2) {
        #pragma unroll
        for (int mt = 0; mt < 4; ++mt) {
            c0[mt] = c0[mt] + ccomb[jq][mt * 3 + 0][lane];
            c1[mt] = c1[mt] + ccomb[jq][mt * 3 + 1][lane];
            cs[mt] = cs[mt] + ccomb[jq][mt * 3 + 2][lane];
        }
    }
    __syncthreads();
    if (jq == 1) {
        #pragma unroll
        for (int mt = 0; mt < 4; ++mt) {
            ccomb[0][mt * 3 + 0][lane] = c0[mt];
            ccomb[0][mt * 3 + 1][lane] = c1[mt];
            ccomb[0][mt * 3 + 2][lane] = cs[mt];
        }
    }
    __syncthreads();
    if (jq == 0) {
        #pragma unroll
        for (int mt = 0; mt < 4; ++mt) {
            c0[mt] = c0[mt] + ccomb[0][mt * 3 + 0][lane];
            c1[mt] = c1[mt] + ccomb[0][mt * 3 + 1][lane];
            cs[mt] = cs[mt] + ccomb[0][mt * 3 + 2][lane];

            // C/D: col=il (d), row=ql*4+reg (i); cs[mt][reg] = S_i
            float* ob = out + (size_t)(b * NN + i0 + mt * 16 + ql * 4) * NOUT + h * ND + il;
            #pragma unroll
            for (int reg = 0; reg < 4; ++reg) {
                const float r = 1.0f / cs[mt][reg];
                ob[reg * NOUT]      = c0[mt][reg] * r;
                ob[reg * NOUT + 16] = c1[mt][reg] * r;
            }
        }
    }
}

// ---------------------------------------------------------------------------
extern "C" void kernel_launch(void* const* d_in, const int* in_sizes, int n_in,
                              void* d_out, int out_size, void* d_ws, size_t ws_size,
                              hipStream_t stream) {
    (void)in_sizes; (void)n_in; (void)out_size; (void)ws_size;
    const float* vertex = (const float*)d_in[0];
    const float* w_vert = (const float*)d_in[1];
    const float* attn_w = (const float*)d_in[2];
    float* out = (float*)d_out;

    char* ws = (char*)d_ws;
    unsigned short* gT = (unsigned short*)ws;                          // 4 MB
    float* ssT = (float*)(ws + ((size_t)NB * NH * ND * NN * 2));
    float* sdT = ssT + (size_t)NB * NH * NN;

    gat_gemm_kernel<<<dim3(128, NH), 256, 0, stream>>>(vertex, w_vert, attn_w,
                                                       gT, ssT, sdT);
    gat_attn_kernel<<<1024, 256, 0, stream>>>(gT, ssT, sdT, out);
}